// Round 5
// baseline (256.247 us; speedup 1.0000x reference)
//
#include <hip/hip_runtime.h>
#include <hip/hip_bf16.h>

#define NDIM 64
#define BP   72      // bf16 LDS pitch: 144 B rows -> ds_read_b128 frag reads are phase-conflict-free
#define DT_  0.01f

typedef __attribute__((ext_vector_type(8)))  short bf16x8;
typedef __attribute__((ext_vector_type(16))) float f32x16;

struct Frag { bf16x8 f[4]; };

// ---------------- bf16 helpers ----------------

__device__ __forceinline__ unsigned short f2b(float x) {
    __hip_bfloat16 h = __float2bfloat16(x);          // RTNE
    return __builtin_bit_cast(unsigned short, h);
}
__device__ __forceinline__ float b2f(unsigned short u) {
    unsigned int v = (unsigned int)u << 16;
    return __builtin_bit_cast(float, v);
}
__device__ __forceinline__ unsigned int f2b2(float lo, float hi) {
    return (unsigned int)f2b(lo) | ((unsigned int)f2b(hi) << 16);
}

// ---------------- fragment / tile helpers (32x32x16 MFMA) ----------------
// Wave w: rw = 32*(w>>1), cw = 32*(w&1).
// A/B frag: lane holds M[rb + (lane&31)][j*16 + (lane>>5)*8 + 0..7]  (one b128)
// C/D slot r: row = rw + (r&3) + 8*(r>>2) + 4*(lane>>5), col = cw + (lane&31)

__device__ __forceinline__ bf16x8 ldfrag(const unsigned short* M, int rb, int j, int ln, int hq) {
    return *(const bf16x8*)&M[(rb + ln) * BP + j * 16 + hq * 8];
}

// operator B-frags (rows cw+ln) straight from fp32 global, packed cvt to bf16
__device__ __forceinline__ void ldopf(Frag& F, const float* __restrict__ p,
                                      int ln, int hq, int cw) {
#pragma unroll
    for (int j = 0; j < 4; ++j) {
        const float* q = &p[(cw + ln) * 64 + j * 16 + hq * 8];
        float4 u = *(const float4*)q;
        float4 v = *(const float4*)(q + 4);
        uint4 o;
        o.x = f2b2(u.x, u.y); o.y = f2b2(u.z, u.w);
        o.z = f2b2(v.x, v.y); o.w = f2b2(v.z, v.w);
        F.f[j] = __builtin_bit_cast(bf16x8, o);
    }
}

// W-frags: rows cw+ln of W = I - Uh
__device__ __forceinline__ void ldWfrag(Frag& F, const float* __restrict__ Uh,
                                        int ln, int hq, int cw) {
    const int n = cw + ln;
#pragma unroll
    for (int j = 0; j < 4; ++j) {
        const int k0 = j * 16 + hq * 8;
        const float* q = &Uh[n * 64 + k0];
        float4 u = *(const float4*)q;
        float4 v = *(const float4*)(q + 4);
        float wv[8] = {-u.x, -u.y, -u.z, -u.w, -v.x, -v.y, -v.z, -v.w};
#pragma unroll
        for (int e = 0; e < 8; ++e)
            if (n == k0 + e) wv[e] += 1.f;
        uint4 o;
        o.x = f2b2(wv[0], wv[1]); o.y = f2b2(wv[2], wv[3]);
        o.z = f2b2(wv[4], wv[5]); o.w = f2b2(wv[6], wv[7]);
        F.f[j] = __builtin_bit_cast(bf16x8, o);
    }
}

// C = A @ F^T (A rows rb.. from LDS, F = operator row-frags in regs)
template <bool ACC>
__device__ __forceinline__ void ntg(const unsigned short* A, const Frag& F, f32x16& acc,
                                    int ln, int hq, int rb) {
    if (!ACC) {
#pragma unroll
        for (int r = 0; r < 16; ++r) acc[r] = 0.f;
    }
#pragma unroll
    for (int j = 0; j < 4; ++j)
        acc = __builtin_amdgcn_mfma_f32_32x32x16_bf16(ldfrag(A, rb, j, ln, hq), F.f[j], acc, 0, 0, 0);
}

// two GEMMs sharing A-frags
__device__ __forceinline__ void ntg2(const unsigned short* A, const Frag& Fa, const Frag& Fb,
                                     f32x16& c0, f32x16& c1, int ln, int hq, int rb) {
#pragma unroll
    for (int r = 0; r < 16; ++r) { c0[r] = 0.f; c1[r] = 0.f; }
#pragma unroll
    for (int j = 0; j < 4; ++j) {
        bf16x8 a = ldfrag(A, rb, j, ln, hq);
        c0 = __builtin_amdgcn_mfma_f32_32x32x16_bf16(a, Fa.f[j], c0, 0, 0, 0);
        c1 = __builtin_amdgcn_mfma_f32_32x32x16_bf16(a, Fb.f[j], c1, 0, 0, 0);
    }
}

// transposed store: slot (row,col) -> LDS[col][row]; b64 vector writes
__device__ __forceinline__ void stT(unsigned short* D, const f32x16& v,
                                    int ln, int hq, int rw, int cw) {
#pragma unroll
    for (int g = 0; g < 4; ++g) {
        uint2 o;
        o.x = f2b2(v[4 * g + 0], v[4 * g + 1]);
        o.y = f2b2(v[4 * g + 2], v[4 * g + 3]);
        *(uint2*)&D[(cw + ln) * BP + rw + 8 * g + 4 * hq] = o;
    }
}

// transposed read into slot order (S row-major; returns S^T slots)
__device__ __forceinline__ void ldT(float* r, const unsigned short* S,
                                    int ln, int hq, int rw, int cw) {
#pragma unroll
    for (int g = 0; g < 4; ++g) {
        uint2 u = *(const uint2*)&S[(cw + ln) * BP + rw + 8 * g + 4 * hq];
        unsigned short o[4];
        *(uint2*)o = u;
#pragma unroll
        for (int j = 0; j < 4; ++j) r[4 * g + j] = b2f(o[j]);
    }
}

// ---------------- single fused kernel: one workgroup per density matrix ----------------
// All sandwiches M X M^T with X symmetric run as two NT gemms through stT round-trips.
// V = I + W + W^2 (W = I - Uh) computed per block with one extra MFMA gemm; the three
// U1 sandwiches are merged: out = U1(M1)U1^T + c16*S2, rho2 = U1(M2)U1^T with
// M1 = X + (c16-c12)S0 + c23*H1, M2 = X - c12*S0 + DT*H1, H1 = V S1 V^T.

__global__ void __launch_bounds__(256) krk_main(const float* __restrict__ rho0,
                                                const float* __restrict__ UhG,
                                                const float* __restrict__ U1G,
                                                const float* __restrict__ L0G,
                                                const float* __restrict__ LhG,
                                                const float* __restrict__ L1G,
                                                float* __restrict__ out) {
    __shared__ unsigned short B0[NDIM * BP];
    __shared__ unsigned short B1[NDIM * BP];
    __shared__ unsigned short B2[NDIM * BP];
    __shared__ unsigned short B3[NDIM * BP];

    const int tid = threadIdx.x;
    const int w = tid >> 6, lane = tid & 63, ln = lane & 31, hq = lane >> 5;
    const int rw = 32 * (w >> 1), cw = 32 * (w & 1);
    const float* rho = rho0 + (size_t)blockIdx.x * (NDIM * NDIM);

    const float c12 = 0.5f * DT_, c16 = DT_ / 6.f, c23 = 2.f * DT_ / 3.f;

    f32x16 t0, t1, s0, a1;
    Frag Fa, Fb, Fu, Fv, Fw;

    // ---- P0: stage rho0 -> B0, W -> B1 (row-major), W^T -> B2; W row-frags -> Fw
#pragma unroll
    for (int i = 0; i < 4; ++i) {
        int flat = (tid + i * 256) * 4;
        int r = flat >> 6, c = flat & 63;
        float4 v = *(const float4*)&rho[flat];
        uint2 o; o.x = f2b2(v.x, v.y); o.y = f2b2(v.z, v.w);
        *(uint2*)&B0[r * BP + c] = o;

        float4 u = *(const float4*)&UhG[flat];
        float wv[4] = {-u.x, -u.y, -u.z, -u.w};
#pragma unroll
        for (int j = 0; j < 4; ++j)
            if (r == c + j) wv[j] += 1.f;
        unsigned short ws[4] = {f2b(wv[0]), f2b(wv[1]), f2b(wv[2]), f2b(wv[3])};
        *(uint2*)&B1[r * BP + c] = *(uint2*)ws;
#pragma unroll
        for (int j = 0; j < 4; ++j) B2[(c + j) * BP + r] = ws[j];   // W^T
    }
    ldWfrag(Fw, UhG, ln, hq, cw);
    __syncthreads();

    // ---- P1: (W^T)^2 slots = ntg(B2=W^T, Fw); V^T slots = I + W^T + (W^T)^2 -> stT -> B3 = V
    ntg<false>(B2, Fw, t0, ln, hq, rw);
    {
        float wts[16];
        ldT(wts, B1, ln, hq, rw, cw);            // W^T slots
        f32x16 vt;
#pragma unroll
        for (int r = 0; r < 16; ++r) {
            int row = rw + (r & 3) + 8 * (r >> 2) + 4 * hq;
            vt[r] = ((row == cw + ln) ? 1.f : 0.f) + wts[r] + t0[r];
        }
        stT(B3, vt, ln, hq, rw, cw);             // B3 row-major = V
    }
    ldopf(Fa, L0G, ln, hq, cw);                  // L00 (prefetch)
    ldopf(Fb, L0G + 4096, ln, hq, cw);           // L01
    __syncthreads();

    // ---- P2: Fv = V row-frags; R0 = rho0@L00^T -> B1 (= L00 rho0); R1 -> B2 (= L01 rho0)
#pragma unroll
    for (int j = 0; j < 4; ++j) Fv.f[j] = ldfrag(B3, cw, j, ln, hq);
    ntg2(B0, Fa, Fb, t0, t1, ln, hq, rw);
    stT(B1, t0, ln, hq, rw, cw);
    stT(B2, t1, ln, hq, rw, cw);
    __syncthreads();

    // ---- P3: s0 = S0 slots; X = rho0 + c12*S0 -> B0 in place (wave-disjoint, read-before-write)
    ntg<false>(B1, Fa, s0, ln, hq, rw);
    ntg<true >(B2, Fb, s0, ln, hq, rw);
    {
        float r0s[16];
        ldT(r0s, B0, ln, hq, rw, cw);
        f32x16 X;
#pragma unroll
        for (int r = 0; r < 16; ++r) X[r] = r0s[r] + c12 * s0[r];
        stT(B0, X, ln, hq, rw, cw);
    }
    ldopf(Fu, UhG, ln, hq, cw);                  // Uh (prefetch)
    __syncthreads();

    // ---- P4: Rh = X@Uh^T -> B3 (= Uh X)
    ntg<false>(B0, Fu, t0, ln, hq, rw);
    stT(B3, t0, ln, hq, rw, cw);
    __syncthreads();

    // ---- P5: rho1 = (Uh X)@Uh^T -> B1
    ntg<false>(B3, Fu, t0, ln, hq, rw);
    stT(B1, t0, ln, hq, rw, cw);
    ldopf(Fa, LhG, ln, hq, cw);                  // Lh0 (prefetch)
    ldopf(Fb, LhG + 4096, ln, hq, cw);           // Lh1
    __syncthreads();

    // ---- P6: Ra = rho1@Lh0^T -> B2 ; Rb = rho1@Lh1^T -> B3
    ntg2(B1, Fa, Fb, t0, t1, ln, hq, rw);
    stT(B2, t0, ln, hq, rw, cw);
    stT(B3, t1, ln, hq, rw, cw);
    __syncthreads();

    // ---- P7: s1 = S1 slots -> stT B1 (= S1)
    ntg<false>(B2, Fa, t0, ln, hq, rw);
    ntg<true >(B3, Fb, t0, ln, hq, rw);
    stT(B1, t0, ln, hq, rw, cw);
    __syncthreads();

    // ---- P8: Rv = S1@V^T -> B2 (= V S1)
    ntg<false>(B1, Fv, t0, ln, hq, rw);
    stT(B2, t0, ln, hq, rw, cw);
    __syncthreads();

    // ---- P9: h1 = H1 slots; M1 -> B1, M2 -> B3
    {
        f32x16 h1;
        ntg<false>(B2, Fv, h1, ln, hq, rw);
        float xs[16];
        ldT(xs, B0, ln, hq, rw, cw);             // X slots
        f32x16 M1, M2;
#pragma unroll
        for (int r = 0; r < 16; ++r) {
            M1[r] = xs[r] + (c16 - c12) * s0[r] + c23 * h1[r];
            M2[r] = xs[r] - c12 * s0[r] + DT_ * h1[r];
        }
        stT(B1, M1, ln, hq, rw, cw);
        stT(B3, M2, ln, hq, rw, cw);
    }
    ldopf(Fu, U1G, ln, hq, cw);                  // U1 (prefetch)
    __syncthreads();

    // ---- P10: Rm1 = M1@U1^T -> B0 (X dead) ; Rm2 = M2@U1^T -> B2
    ntg<false>(B1, Fu, t0, ln, hq, rw);
    stT(B0, t0, ln, hq, rw, cw);
    ntg<false>(B3, Fu, t1, ln, hq, rw);
    stT(B2, t1, ln, hq, rw, cw);
    __syncthreads();

    // ---- P11: a1 = U1 M1 U1^T slots (regs) ; rho2 = U1 M2 U1^T -> B1
    ntg<false>(B0, Fu, a1, ln, hq, rw);
    ntg<false>(B2, Fu, t0, ln, hq, rw);
    stT(B1, t0, ln, hq, rw, cw);
    ldopf(Fa, L1G, ln, hq, cw);                  // L10 (prefetch)
    ldopf(Fb, L1G + 4096, ln, hq, cw);           // L11
    __syncthreads();

    // ---- P12: Rc = rho2@L10^T -> B0 ; Rd = rho2@L11^T -> B3
    ntg2(B1, Fa, Fb, t0, t1, ln, hq, rw);
    stT(B0, t0, ln, hq, rw, cw);
    stT(B3, t1, ln, hq, rw, cw);
    __syncthreads();

    // ---- P13: s2 = S2 slots ; out = a1 + c16*S2 (slot(row,col) stored at [col][row] -- exact)
    {
        f32x16 s2;
        ntg<false>(B0, Fa, s2, ln, hq, rw);
        ntg<true >(B3, Fb, s2, ln, hq, rw);
        float* o = out + (size_t)blockIdx.x * (NDIM * NDIM);
#pragma unroll
        for (int g = 0; g < 4; ++g) {
            float4 v;
            v.x = a1[4 * g + 0] + c16 * s2[4 * g + 0];
            v.y = a1[4 * g + 1] + c16 * s2[4 * g + 1];
            v.z = a1[4 * g + 2] + c16 * s2[4 * g + 2];
            v.w = a1[4 * g + 3] + c16 * s2[4 * g + 3];
            *(float4*)&o[(cw + ln) * 64 + rw + 8 * g + 4 * hq] = v;
        }
    }
}

// ---------------- host launch ----------------

extern "C" void kernel_launch(void* const* d_in, const int* in_sizes, int n_in,
                              void* d_out, int out_size, void* d_ws, size_t ws_size,
                              hipStream_t stream) {
    const float* rho0 = (const float*)d_in[0];
    const float* Uh   = (const float*)d_in[1];
    const float* U1   = (const float*)d_in[2];
    const float* L0   = (const float*)d_in[3];
    const float* Lh   = (const float*)d_in[4];
    const float* L1   = (const float*)d_in[5];
    float* out = (float*)d_out;

    int Bn = in_sizes[0] / (NDIM * NDIM);        // 4096

    krk_main<<<Bn, 256, 0, stream>>>(rho0, Uh, U1, L0, Lh, L1, out);
}

// Round 6
// 180.109 us; speedup vs baseline: 1.4227x; 1.4227x over previous
//
#include <hip/hip_runtime.h>
#include <hip/hip_bf16.h>

#define NDIM 64
#define BP   72      // bf16 LDS pitch: 144 B rows -> ds_read_b128 frag reads 2-way max (free)
#define DT_  0.01f

typedef __attribute__((ext_vector_type(8)))  short bf16x8;
typedef __attribute__((ext_vector_type(16))) float f32x16;

struct Frag { bf16x8 f[4]; };

// ---------------- bf16 helpers ----------------

__device__ __forceinline__ unsigned short f2b(float x) {
    __hip_bfloat16 h = __float2bfloat16(x);          // RTNE
    return __builtin_bit_cast(unsigned short, h);
}
__device__ __forceinline__ float b2f(unsigned short u) {
    unsigned int v = (unsigned int)u << 16;
    return __builtin_bit_cast(float, v);
}
__device__ __forceinline__ unsigned int f2b2(float lo, float hi) {
    return (unsigned int)f2b(lo) | ((unsigned int)f2b(hi) << 16);
}

// ---------------- fragment helpers (32x32x16 MFMA) ----------------
// Wave w: rw = 32*(w>>1), cw = 32*(w&1).
// A/B frag: lane holds M[rb + (lane&31)][j*16 + (lane>>5)*8 + 0..7]  (one b128)
// C/D slot r: row = rw + (r&3) + 8*(r>>2) + 4*(lane>>5), col = cw + (lane&31)

__device__ __forceinline__ bf16x8 ldfrag(const unsigned short* M, int rb, int j, int ln, int hq) {
    return *(const bf16x8*)&M[(rb + ln) * BP + j * 16 + hq * 8];
}

// operator B-frags (rows cw+ln) from bf16 ws, pitch 64
__device__ __forceinline__ void ldg_op(Frag& F, const unsigned short* __restrict__ p,
                                       int ln, int hq, int cw) {
#pragma unroll
    for (int j = 0; j < 4; ++j)
        F.f[j] = *(const bf16x8*)&p[(cw + ln) * 64 + j * 16 + hq * 8];
}

// W-frags: rows cw+ln of W = I - Uh (fp32 global, setup only)
__device__ __forceinline__ void ldWfrag(Frag& F, const float* __restrict__ Uh,
                                        int ln, int hq, int cw) {
    const int n = cw + ln;
#pragma unroll
    for (int j = 0; j < 4; ++j) {
        const int k0 = j * 16 + hq * 8;
        const float* q = &Uh[n * 64 + k0];
        float4 u = *(const float4*)q;
        float4 v = *(const float4*)(q + 4);
        float wv[8] = {-u.x, -u.y, -u.z, -u.w, -v.x, -v.y, -v.z, -v.w};
#pragma unroll
        for (int e = 0; e < 8; ++e)
            if (n == k0 + e) wv[e] += 1.f;
        uint4 o;
        o.x = f2b2(wv[0], wv[1]); o.y = f2b2(wv[2], wv[3]);
        o.z = f2b2(wv[4], wv[5]); o.w = f2b2(wv[6], wv[7]);
        F.f[j] = __builtin_bit_cast(bf16x8, o);
    }
}

// C = A @ F^T (A rows rb.. from LDS, F = operator row-frags in regs)
template <bool ACC>
__device__ __forceinline__ void ntg(const unsigned short* A, const Frag& F, f32x16& acc,
                                    int ln, int hq, int rb) {
    if (!ACC) {
#pragma unroll
        for (int r = 0; r < 16; ++r) acc[r] = 0.f;
    }
#pragma unroll
    for (int j = 0; j < 4; ++j)
        acc = __builtin_amdgcn_mfma_f32_32x32x16_bf16(ldfrag(A, rb, j, ln, hq), F.f[j], acc, 0, 0, 0);
}

// two GEMMs sharing A-frags
__device__ __forceinline__ void ntg2(const unsigned short* A, const Frag& Fa, const Frag& Fb,
                                     f32x16& c0, f32x16& c1, int ln, int hq, int rb) {
#pragma unroll
    for (int r = 0; r < 16; ++r) { c0[r] = 0.f; c1[r] = 0.f; }
#pragma unroll
    for (int j = 0; j < 4; ++j) {
        bf16x8 a = ldfrag(A, rb, j, ln, hq);
        c0 = __builtin_amdgcn_mfma_f32_32x32x16_bf16(a, Fa.f[j], c0, 0, 0, 0);
        c1 = __builtin_amdgcn_mfma_f32_32x32x16_bf16(a, Fb.f[j], c1, 0, 0, 0);
    }
}

// transposed store: slot (row,col) -> LDS[col][row]; b64 vector writes
__device__ __forceinline__ void stT(unsigned short* D, const f32x16& v,
                                    int ln, int hq, int rw, int cw) {
#pragma unroll
    for (int g = 0; g < 4; ++g) {
        uint2 o;
        o.x = f2b2(v[4 * g + 0], v[4 * g + 1]);
        o.y = f2b2(v[4 * g + 2], v[4 * g + 3]);
        *(uint2*)&D[(cw + ln) * BP + rw + 8 * g + 4 * hq] = o;
    }
}

// transposed read into slot order (S row-major; returns S^T slots == S slots if symmetric)
__device__ __forceinline__ void ldT(float* r, const unsigned short* S,
                                    int ln, int hq, int rw, int cw) {
#pragma unroll
    for (int g = 0; g < 4; ++g) {
        uint2 u = *(const uint2*)&S[(cw + ln) * BP + rw + 8 * g + 4 * hq];
        unsigned short o[4];
        *(uint2*)o = u;
#pragma unroll
        for (int j = 0; j < 4; ++j) r[4 * g + j] = b2f(o[j]);
    }
}

// ---------------- setup: blocks 0-7 cast operators; block 8 computes V = I + W + W^2 ----------
// ws layout (bf16, 4096 each): 0=Uh 1=U1 2=L00 3=L01 4=Lh0 5=Lh1 6=L10 7=L11 8=V

__global__ void __launch_bounds__(256) krk_setup(const float* __restrict__ Uh,
                                                 const float* __restrict__ U1,
                                                 const float* __restrict__ L0,
                                                 const float* __restrict__ Lh,
                                                 const float* __restrict__ L1,
                                                 unsigned short* __restrict__ ws) {
    __shared__ unsigned short sW [NDIM * BP];   // W row-major
    __shared__ unsigned short sWt[NDIM * BP];   // W^T

    const int blk = blockIdx.x, tid = threadIdx.x;

    if (blk < 8) {
        const float* srcs[8] = {Uh, U1, L0, L0 + 4096, Lh, Lh + 4096, L1, L1 + 4096};
        const float* s = srcs[blk];
        unsigned short* d = ws + blk * 4096;
#pragma unroll
        for (int i = 0; i < 4; ++i) {
            int flat = (tid + i * 256) * 4;
            float4 v = *(const float4*)&s[flat];
            uint2 o; o.x = f2b2(v.x, v.y); o.y = f2b2(v.z, v.w);
            *(uint2*)&d[flat] = o;
        }
        return;
    }

    // ---- block 8: V = I + W + W^2  (W = I - Uh), store row-major bf16
    const int lane = tid & 63, w = tid >> 6, ln = lane & 31, hq = lane >> 5;
    const int rw = 32 * (w >> 1), cw = 32 * (w & 1);

#pragma unroll
    for (int i = 0; i < 4; ++i) {
        int flat = (tid + i * 256) * 4;
        int r = flat >> 6, c = flat & 63;
        float4 u = *(const float4*)&Uh[flat];
        float wv[4] = {-u.x, -u.y, -u.z, -u.w};
#pragma unroll
        for (int j = 0; j < 4; ++j)
            if (r == c + j) wv[j] += 1.f;
        unsigned short o[4] = {f2b(wv[0]), f2b(wv[1]), f2b(wv[2]), f2b(wv[3])};
        *(uint2*)&sW[r * BP + c] = *(uint2*)o;
#pragma unroll
        for (int j = 0; j < 4; ++j) sWt[(c + j) * BP + r] = o[j];
    }
    Frag Fw;
    ldWfrag(Fw, Uh, ln, hq, cw);
    __syncthreads();

    f32x16 t0;
    ntg<false>(sWt, Fw, t0, ln, hq, rw);         // (W^2)^T slots
    float wts[16];
    ldT(wts, sW, ln, hq, rw, cw);                // W^T slots
    unsigned short* ws8 = ws + 8 * 4096;
#pragma unroll
    for (int g = 0; g < 4; ++g) {
        uint2 o;
        float v0, v1;
#pragma unroll
        for (int j = 0; j < 4; j += 2) {
            int r0 = 4 * g + j, r1 = r0 + 1;
            int row0 = rw + (r0 & 3) + 8 * g + 4 * hq;
            int row1 = row0 + 1;
            v0 = ((row0 == cw + ln) ? 1.f : 0.f) + wts[r0] + t0[r0];
            v1 = ((row1 == cw + ln) ? 1.f : 0.f) + wts[r1] + t0[r1];
            if (j == 0) o.x = f2b2(v0, v1); else o.y = f2b2(v0, v1);
        }
        // V^T slot (row,col) -> V[col][row]: contiguous rows -> b64 store
        *(uint2*)&ws8[(cw + ln) * 64 + rw + 8 * g + 4 * hq] = o;
    }
}

// ---------------- main: one workgroup per density matrix, 13 phases, 4 LDS buffers ----------
// out = U1 M1 U1^T + c16*S2,  rho2 = U1 M2 U1^T,  H1 = V S1 V^T,
// M1 = X + (c16-c12)S0 + c23*H1,  M2 = X - c12*S0 + DT*H1,  X = rho0 + c12*S0.

__global__ void __launch_bounds__(256) krk_main(const float* __restrict__ rho0,
                                                const unsigned short* __restrict__ ws,
                                                float* __restrict__ out) {
    __shared__ unsigned short B0[NDIM * BP];
    __shared__ unsigned short B1[NDIM * BP];
    __shared__ unsigned short B2[NDIM * BP];
    __shared__ unsigned short B3[NDIM * BP];

    const int tid = threadIdx.x;
    const int w = tid >> 6, lane = tid & 63, ln = lane & 31, hq = lane >> 5;
    const int rw = 32 * (w >> 1), cw = 32 * (w & 1);
    const float* rho = rho0 + (size_t)blockIdx.x * (NDIM * NDIM);

    const float c12 = 0.5f * DT_, c16 = DT_ / 6.f, c23 = 2.f * DT_ / 3.f;

    f32x16 t0, t1, s0, a1;
    Frag Fa, Fb, Fc;

    // ---- P0: stage rho0 -> B0 ; prefetch L00,L01
#pragma unroll
    for (int i = 0; i < 4; ++i) {
        int flat = (tid + i * 256) * 4;
        int r = flat >> 6, c = flat & 63;
        float4 v = *(const float4*)&rho[flat];
        uint2 o; o.x = f2b2(v.x, v.y); o.y = f2b2(v.z, v.w);
        *(uint2*)&B0[r * BP + c] = o;
    }
    ldg_op(Fa, ws + 2 * 4096, ln, hq, cw);        // L00
    ldg_op(Fb, ws + 3 * 4096, ln, hq, cw);        // L01
    __syncthreads();

    // ---- P1: R0 = rho0@L00^T -> B1 ; R1 = rho0@L01^T -> B2
    ntg2(B0, Fa, Fb, t0, t1, ln, hq, rw);
    stT(B1, t0, ln, hq, rw, cw);
    stT(B2, t1, ln, hq, rw, cw);
    __syncthreads();

    // ---- P2: s0 = S0 slots (regs) ; X = rho0 + c12*S0 -> B0 (same-lane rewrite) ; prefetch Uh
    ntg<false>(B1, Fa, s0, ln, hq, rw);
    ntg<true >(B2, Fb, s0, ln, hq, rw);
    {
        float r0s[16];
        ldT(r0s, B0, ln, hq, rw, cw);
        f32x16 X;
#pragma unroll
        for (int r = 0; r < 16; ++r) X[r] = r0s[r] + c12 * s0[r];
        stT(B0, X, ln, hq, rw, cw);
    }
    ldg_op(Fc, ws + 0 * 4096, ln, hq, cw);        // Uh
    __syncthreads();

    // ---- P3: Rh = X@Uh^T -> B3
    ntg<false>(B0, Fc, t0, ln, hq, rw);
    stT(B3, t0, ln, hq, rw, cw);
    __syncthreads();

    // ---- P4: rho1 = (Uh X)@Uh^T -> B1 ; prefetch Lh0,Lh1
    ntg<false>(B3, Fc, t0, ln, hq, rw);
    stT(B1, t0, ln, hq, rw, cw);
    ldg_op(Fa, ws + 4 * 4096, ln, hq, cw);        // Lh0
    ldg_op(Fb, ws + 5 * 4096, ln, hq, cw);        // Lh1
    __syncthreads();

    // ---- P5: Ra = rho1@Lh0^T -> B2 ; Rb = rho1@Lh1^T -> B3
    ntg2(B1, Fa, Fb, t0, t1, ln, hq, rw);
    stT(B2, t0, ln, hq, rw, cw);
    stT(B3, t1, ln, hq, rw, cw);
    __syncthreads();

    // ---- P6: S1 -> B1 ; prefetch V
    ntg<false>(B2, Fa, t0, ln, hq, rw);
    ntg<true >(B3, Fb, t0, ln, hq, rw);
    stT(B1, t0, ln, hq, rw, cw);
    ldg_op(Fc, ws + 8 * 4096, ln, hq, cw);        // V
    __syncthreads();

    // ---- P7: Rv = S1@V^T -> B2 (= V S1)
    ntg<false>(B1, Fc, t0, ln, hq, rw);
    stT(B2, t0, ln, hq, rw, cw);
    __syncthreads();

    // ---- P8: h1 = H1 slots ; M1 -> B1, M2 -> B3 ; then prefetch U1
    {
        f32x16 h1;
        ntg<false>(B2, Fc, h1, ln, hq, rw);
        float xs[16];
        ldT(xs, B0, ln, hq, rw, cw);              // X slots (B0 untouched since P3 read)
        f32x16 M1, M2;
#pragma unroll
        for (int r = 0; r < 16; ++r) {
            M1[r] = xs[r] + (c16 - c12) * s0[r] + c23 * h1[r];
            M2[r] = xs[r] - c12 * s0[r] + DT_ * h1[r];
        }
        stT(B1, M1, ln, hq, rw, cw);
        stT(B3, M2, ln, hq, rw, cw);
    }
    ldg_op(Fc, ws + 1 * 4096, ln, hq, cw);        // U1 (after V's last use)
    __syncthreads();

    // ---- P9: Rm1 = M1@U1^T -> B0 ; Rm2 = M2@U1^T -> B2
    ntg<false>(B1, Fc, t0, ln, hq, rw);
    stT(B0, t0, ln, hq, rw, cw);
    ntg<false>(B3, Fc, t1, ln, hq, rw);
    stT(B2, t1, ln, hq, rw, cw);
    __syncthreads();

    // ---- P10: a1 = U1 M1 U1^T slots (regs) ; rho2 -> B1 ; prefetch L10,L11
    ntg<false>(B0, Fc, a1, ln, hq, rw);
    ntg<false>(B2, Fc, t0, ln, hq, rw);
    stT(B1, t0, ln, hq, rw, cw);
    ldg_op(Fa, ws + 6 * 4096, ln, hq, cw);        // L10
    ldg_op(Fb, ws + 7 * 4096, ln, hq, cw);        // L11
    __syncthreads();

    // ---- P11: Rc = rho2@L10^T -> B0 ; Rd = rho2@L11^T -> B2
    ntg2(B1, Fa, Fb, t0, t1, ln, hq, rw);
    stT(B0, t0, ln, hq, rw, cw);
    stT(B2, t1, ln, hq, rw, cw);
    __syncthreads();

    // ---- P12: s2 = S2 slots ; out = a1 + c16*S2 (slot(row,col) stored at [col][row] -- exact)
    ntg<false>(B0, Fa, t0, ln, hq, rw);
    ntg<true >(B2, Fb, t0, ln, hq, rw);
    {
        float* o = out + (size_t)blockIdx.x * (NDIM * NDIM);
#pragma unroll
        for (int g = 0; g < 4; ++g) {
            float4 v;
            v.x = a1[4 * g + 0] + c16 * t0[4 * g + 0];
            v.y = a1[4 * g + 1] + c16 * t0[4 * g + 1];
            v.z = a1[4 * g + 2] + c16 * t0[4 * g + 2];
            v.w = a1[4 * g + 3] + c16 * t0[4 * g + 3];
            *(float4*)&o[(cw + ln) * 64 + rw + 8 * g + 4 * hq] = v;
        }
    }
}

// ---------------- host launch ----------------

extern "C" void kernel_launch(void* const* d_in, const int* in_sizes, int n_in,
                              void* d_out, int out_size, void* d_ws, size_t ws_size,
                              hipStream_t stream) {
    const float* rho0 = (const float*)d_in[0];
    const float* Uh   = (const float*)d_in[1];
    const float* U1   = (const float*)d_in[2];
    const float* L0   = (const float*)d_in[3];
    const float* Lh   = (const float*)d_in[4];
    const float* L1   = (const float*)d_in[5];
    float* out = (float*)d_out;
    unsigned short* ws = (unsigned short*)d_ws;   // 9 bf16 64x64 matrices = 73728 B

    int Bn = in_sizes[0] / (NDIM * NDIM);         // 4096

    krk_setup<<<9, 256, 0, stream>>>(Uh, U1, L0, Lh, L1, ws);
    krk_main<<<Bn, 256, 0, stream>>>(rho0, ws, out);
}